// Round 1
// baseline (798.809 us; speedup 1.0000x reference)
//
#include <hip/hip_runtime.h>
#include <math.h>

#define NAG 10
#define PP  65536
#define EE  64
#define INW 16

__global__ __launch_bounds__(256) void mpnn_fused(
    const float* __restrict__ inp,
    const float* __restrict__ W_enc, const float* __restrict__ b_enc,
    const float* __restrict__ W_goal, const float* __restrict__ b_goal,
    const float* __restrict__ Wq, const float* __restrict__ Wk,
    const float* __restrict__ Wv, const float* __restrict__ Wo,
    const float* __restrict__ W_upd, const float* __restrict__ b_upd,
    float* __restrict__ out)
{
    __shared__ __align__(16) float ai_s[4][NAG][14];
    __shared__ __align__(16) float goal_s[4][2];
    __shared__ __align__(16) float h_s[4][NAG][EE];
    __shared__ __align__(16) float k_s[4][NAG][EE];   // reused for mo (= m @ Wo)
    __shared__ __align__(16) float v_s[4][NAG][EE];
    __shared__ __align__(16) float q_s[4][NAG][EE];   // reused for m (= attn @ V)
    __shared__ __align__(16) float attn_s[4][NAG][NAG];

    const int tid = threadIdx.x;
    const int lp  = tid >> 6;     // which p within block (one wave each)
    const int e   = tid & 63;     // feature column
    const int p   = (blockIdx.x << 2) + lp;

    // ---- stage inputs: agent rows (first 14 cols) + goal (cols 14..15 of row p)
    if (e < 14) {
        #pragma unroll
        for (int a = 0; a < NAG; ++a)
            ai_s[lp][a][e] = inp[(size_t)(a * PP + p) * INW + e];
    }
    if (e < 2) goal_s[lp][e] = inp[(size_t)p * INW + 14 + e];
    __syncthreads();

    // ---- h = relu(agent_inp @ W_enc + b_enc)
    {
        float acc[NAG];
        float b = b_enc[e];
        #pragma unroll
        for (int a = 0; a < NAG; ++a) acc[a] = b;
        #pragma unroll
        for (int d = 0; d < 14; ++d) {
            float w = W_enc[d * EE + e];
            #pragma unroll
            for (int a = 0; a < NAG; ++a) acc[a] = fmaf(ai_s[lp][a][d], w, acc[a]);
        }
        #pragma unroll
        for (int a = 0; a < NAG; ++a) h_s[lp][a][e] = fmaxf(acc[a], 0.f);
    }
    // goal encoder (leader's h2), kept in register
    float h2l = fmaxf(fmaf(goal_s[lp][0], W_goal[e],
                      fmaf(goal_s[lp][1], W_goal[EE + e], b_goal[e])), 0.f);
    __syncthreads();

    // ---- Q, K, V = h @ Wq/Wk/Wv  (fused pass: 1 LDS b128 read feeds 12 FMA)
    {
        float qa[NAG], ka[NAG], va[NAG];
        #pragma unroll
        for (int a = 0; a < NAG; ++a) { qa[a] = 0.f; ka[a] = 0.f; va[a] = 0.f; }
        for (int d4 = 0; d4 < 16; ++d4) {
            const int d = d4 * 4;
            float wq0 = Wq[(d+0)*EE+e], wq1 = Wq[(d+1)*EE+e], wq2 = Wq[(d+2)*EE+e], wq3 = Wq[(d+3)*EE+e];
            float wk0 = Wk[(d+0)*EE+e], wk1 = Wk[(d+1)*EE+e], wk2 = Wk[(d+2)*EE+e], wk3 = Wk[(d+3)*EE+e];
            float wv0 = Wv[(d+0)*EE+e], wv1 = Wv[(d+1)*EE+e], wv2 = Wv[(d+2)*EE+e], wv3 = Wv[(d+3)*EE+e];
            #pragma unroll
            for (int a = 0; a < NAG; ++a) {
                float4 hv = *reinterpret_cast<const float4*>(&h_s[lp][a][d]);
                qa[a] = fmaf(hv.x, wq0, fmaf(hv.y, wq1, fmaf(hv.z, wq2, fmaf(hv.w, wq3, qa[a]))));
                ka[a] = fmaf(hv.x, wk0, fmaf(hv.y, wk1, fmaf(hv.z, wk2, fmaf(hv.w, wk3, ka[a]))));
                va[a] = fmaf(hv.x, wv0, fmaf(hv.y, wv1, fmaf(hv.z, wv2, fmaf(hv.w, wv3, va[a]))));
            }
        }
        #pragma unroll
        for (int a = 0; a < NAG; ++a) {
            q_s[lp][a][e] = qa[a];
            k_s[lp][a][e] = ka[a];
            v_s[lp][a][e] = va[a];
        }
    }
    __syncthreads();

    // ---- compat = (Q K^T) * scale with mask (k==q or k==0 -> -inf)
    {
        const float scale = 0.125f;   // 1/sqrt(64)
        for (int idx = e; idx < NAG * NAG; idx += 64) {
            const int q = idx / NAG, k = idx % NAG;
            float c;
            if (k == q || k == 0) {
                c = -INFINITY;
            } else {
                float cs = 0.f;
                #pragma unroll
                for (int d4 = 0; d4 < 16; ++d4) {
                    float4 qv = *reinterpret_cast<const float4*>(&q_s[lp][q][d4*4]);
                    float4 kv = *reinterpret_cast<const float4*>(&k_s[lp][k][d4*4]);
                    cs = fmaf(qv.x, kv.x, fmaf(qv.y, kv.y, fmaf(qv.z, kv.z, fmaf(qv.w, kv.w, cs))));
                }
                c = cs * scale;
            }
            attn_s[lp][q][k] = c;
        }
    }
    __syncthreads();

    // ---- softmax over k, per row q (lanes 0..9)
    if (e < NAG) {
        const int q = e;
        float mx = -INFINITY;
        #pragma unroll
        for (int k = 0; k < NAG; ++k) mx = fmaxf(mx, attn_s[lp][q][k]);
        float ex[NAG];
        float s = 0.f;
        #pragma unroll
        for (int k = 0; k < NAG; ++k) { ex[k] = __expf(attn_s[lp][q][k] - mx); s += ex[k]; }
        const float inv = 1.f / s;
        #pragma unroll
        for (int k = 0; k < NAG; ++k) attn_s[lp][q][k] = ex[k] * inv;
    }
    __syncthreads();

    // ---- m = attn @ V   (then stored into q_s, which is dead)
    {
        float ma[NAG];
        #pragma unroll
        for (int a = 0; a < NAG; ++a) ma[a] = 0.f;
        #pragma unroll
        for (int k = 0; k < NAG; ++k) {
            float vk = v_s[lp][k][e];
            #pragma unroll
            for (int a = 0; a < NAG; ++a) ma[a] = fmaf(attn_s[lp][a][k], vk, ma[a]);
        }
        #pragma unroll
        for (int a = 0; a < NAG; ++a) q_s[lp][a][e] = ma[a];
    }
    __syncthreads();

    // ---- mo = m @ Wo    (stored into k_s, which is dead)
    {
        float mo[NAG];
        #pragma unroll
        for (int a = 0; a < NAG; ++a) mo[a] = 0.f;
        for (int d4 = 0; d4 < 16; ++d4) {
            const int d = d4 * 4;
            float w0 = Wo[(d+0)*EE+e], w1 = Wo[(d+1)*EE+e], w2 = Wo[(d+2)*EE+e], w3 = Wo[(d+3)*EE+e];
            #pragma unroll
            for (int a = 0; a < NAG; ++a) {
                float4 mv = *reinterpret_cast<const float4*>(&q_s[lp][a][d]);
                mo[a] = fmaf(mv.x, w0, fmaf(mv.y, w1, fmaf(mv.z, w2, fmaf(mv.w, w3, mo[a]))));
            }
        }
        #pragma unroll
        for (int a = 0; a < NAG; ++a) k_s[lp][a][e] = mo[a];
    }
    __syncthreads();

    // ---- h1 = relu(concat(h, mo) @ W_upd + b_upd)
    float u[NAG];
    {
        float bu = b_upd[e];
        #pragma unroll
        for (int a = 0; a < NAG; ++a) u[a] = bu;
        for (int d4 = 0; d4 < 16; ++d4) {
            const int d = d4 * 4;
            float w0 = W_upd[(d+0)*EE+e], w1 = W_upd[(d+1)*EE+e], w2 = W_upd[(d+2)*EE+e], w3 = W_upd[(d+3)*EE+e];
            #pragma unroll
            for (int a = 0; a < NAG; ++a) {
                float4 hv = *reinterpret_cast<const float4*>(&h_s[lp][a][d]);
                u[a] = fmaf(hv.x, w0, fmaf(hv.y, w1, fmaf(hv.z, w2, fmaf(hv.w, w3, u[a]))));
            }
        }
        for (int d4 = 0; d4 < 16; ++d4) {
            const int d = d4 * 4;
            float w0 = W_upd[(64+d+0)*EE+e], w1 = W_upd[(64+d+1)*EE+e], w2 = W_upd[(64+d+2)*EE+e], w3 = W_upd[(64+d+3)*EE+e];
            #pragma unroll
            for (int a = 0; a < NAG; ++a) {
                float4 mv = *reinterpret_cast<const float4*>(&k_s[lp][a][d]);
                u[a] = fmaf(mv.x, w0, fmaf(mv.y, w1, fmaf(mv.z, w2, fmaf(mv.w, w3, u[a]))));
            }
        }
        #pragma unroll
        for (int a = 0; a < NAG; ++a) u[a] = fmaxf(u[a], 0.f);
    }

    // ---- outputs
    const float h0 = h_s[lp][0][e];          // agent-0 h (followers' h2)
    out[(size_t)p * 128 + e]      = u[0];    // h_leader[:, 0:64]
    out[(size_t)p * 128 + 64 + e] = h2l;     // h_leader[:, 64:128]
    float* __restrict__ outF = out + (size_t)PP * 128;
    #pragma unroll
    for (int a = 1; a < NAG; ++a) {
        const size_t r = (size_t)(a - 1) * PP + p;
        outF[r * 128 + e]      = u[a];
        outF[r * 128 + 64 + e] = h0;
    }
}

extern "C" void kernel_launch(void* const* d_in, const int* in_sizes, int n_in,
                              void* d_out, int out_size, void* d_ws, size_t ws_size,
                              hipStream_t stream) {
    const float* inp    = (const float*)d_in[0];
    const float* W_enc  = (const float*)d_in[1];
    const float* b_enc  = (const float*)d_in[2];
    const float* W_goal = (const float*)d_in[3];
    const float* b_goal = (const float*)d_in[4];
    const float* Wq     = (const float*)d_in[5];
    const float* Wk     = (const float*)d_in[6];
    const float* Wv     = (const float*)d_in[7];
    const float* Wo     = (const float*)d_in[8];
    const float* W_upd  = (const float*)d_in[9];
    const float* b_upd  = (const float*)d_in[10];

    dim3 grid(PP / 4), block(256);
    hipLaunchKernelGGL(mpnn_fused, grid, block, 0, stream,
                       inp, W_enc, b_enc, W_goal, b_goal,
                       Wq, Wk, Wv, Wo, W_upd, b_upd, (float*)d_out);
}

// Round 2
// 479.083 us; speedup vs baseline: 1.6674x; 1.6674x over previous
//
#include <hip/hip_runtime.h>
#include <math.h>

#define NAG 10
#define PP  65536
#define EE  64
#define INW 16
#define TP  4              // p's per group (one per wave)
#define RR  (TP*NAG)       // 40 real rows
#define SH  72             // LDS stride (bf16 elems) for 64-wide tiles (+8 pad)
#define SX  40             // LDS stride for X tile (k padded to 32, +8)
#define NBLK 1024
#define NGRP (PP/TP)       // 16384

typedef __attribute__((ext_vector_type(8))) short short8;
typedef __attribute__((ext_vector_type(4))) float f32x4;

__device__ __forceinline__ short f2bf(float x){
    unsigned u = __float_as_uint(x);
    u += 0x7FFF + ((u >> 16) & 1);          // RNE
    return (short)(u >> 16);
}
__device__ __forceinline__ float bf2f(short s){
    return __uint_as_float(((unsigned)(unsigned short)s) << 16);
}

__global__ __launch_bounds__(256, 4) void mpnn_mfma(
    const float* __restrict__ inp,
    const float* __restrict__ W_enc, const float* __restrict__ b_enc,
    const float* __restrict__ W_goal, const float* __restrict__ b_goal,
    const float* __restrict__ Wq, const float* __restrict__ Wk,
    const float* __restrict__ Wv, const float* __restrict__ Wo,
    const float* __restrict__ W_upd, const float* __restrict__ b_upd,
    float* __restrict__ out)
{
    __shared__ __align__(16) short Xs [48*SX];
    __shared__ __align__(16) short hs [48*SH];
    __shared__ __align__(16) short qsb[48*SH];   // Q, later reused for m
    __shared__ __align__(16) short ksb[48*SH];   // K, later reused for mo
    __shared__ __align__(16) short vsb[48*SH];   // V
    __shared__ float attn_s[TP][NAG][12];
    __shared__ float goal_s[TP][2];

    const int tid  = threadIdx.x;
    const int w    = tid >> 6;      // wave id == col-tile == p_local for attention
    const int l    = tid & 63;
    const int lrow = l & 15;        // A row / D col within tile
    const int lk   = l >> 4;        // k-group / D row-group
    const int col  = 16*w + lrow;   // global output column of this lane's D frag

    // ---- B-fragment preload (weights stay in registers for the whole kernel)
    short8 fenc, fqw[2], fkw[2], fvw[2], fow[2], fuw[4];
    #pragma unroll
    for (int j = 0; j < 8; ++j) {
        int k = lk*8 + j;
        fenc[j] = (k < 14) ? f2bf(W_enc[k*EE + col]) : (short)0;
    }
    #pragma unroll
    for (int ks = 0; ks < 2; ++ks) {
        #pragma unroll
        for (int j = 0; j < 8; ++j) {
            int k = 32*ks + lk*8 + j;
            fqw[ks][j] = f2bf(Wq[k*EE + col]);
            fkw[ks][j] = f2bf(Wk[k*EE + col]);
            fvw[ks][j] = f2bf(Wv[k*EE + col]);
            fow[ks][j] = f2bf(Wo[k*EE + col]);
        }
    }
    #pragma unroll
    for (int ks = 0; ks < 4; ++ks) {
        #pragma unroll
        for (int j = 0; j < 8; ++j)
            fuw[ks][j] = f2bf(W_upd[(32*ks + lk*8 + j)*EE + col]);
    }
    const float bencv = b_enc[col];
    const float bupdv = b_upd[col];
    const float wg0 = W_goal[l], wg1 = W_goal[EE + l], bg = b_goal[l];

    // zero X once: data writes only touch rows<40, cols<14; rest stays 0
    for (int i = tid; i < 48*SX; i += 256) Xs[i] = 0;

    for (int g = blockIdx.x; g < NGRP; g += NBLK) {
        const int p0 = g * TP;
        __syncthreads();   // WAR: prior iteration's reads of hs/ksb/vsb/Xs done

        // ---- stage X (bf16) + goal
        for (int idx = tid; idx < RR*INW; idx += 256) {
            const int r = idx >> 4, d = idx & 15;
            const int pl = r / NAG, a = r - pl*NAG;
            const float v = inp[((size_t)a*PP + (size_t)(p0 + pl))*INW + d];
            if (d < 14) Xs[r*SX + d] = f2bf(v);
            else if (a == 0) goal_s[pl][d - 14] = v;
        }
        __syncthreads();

        const float h2l = fmaxf(fmaf(goal_s[w][0], wg0,
                           fmaf(goal_s[w][1], wg1, bg)), 0.f);

        // ---- encoder: h = relu(X @ W_enc + b_enc)
        #pragma unroll
        for (int rt = 0; rt < 3; ++rt) {
            const short8 a0 = *reinterpret_cast<const short8*>(&Xs[(16*rt + lrow)*SX + lk*8]);
            f32x4 acc = {0.f,0.f,0.f,0.f};
            acc = __builtin_amdgcn_mfma_f32_16x16x32_bf16(a0, fenc, acc, 0,0,0);
            #pragma unroll
            for (int j = 0; j < 4; ++j)
                hs[(16*rt + lk*4 + j)*SH + col] = f2bf(fmaxf(acc[j] + bencv, 0.f));
        }
        __syncthreads();

        // ---- Q,K,V = h @ Wq/Wk/Wv
        #pragma unroll
        for (int rt = 0; rt < 3; ++rt) {
            const short8 a0 = *reinterpret_cast<const short8*>(&hs[(16*rt + lrow)*SH + lk*8]);
            const short8 a1 = *reinterpret_cast<const short8*>(&hs[(16*rt + lrow)*SH + 32 + lk*8]);
            f32x4 qa = {0.f,0.f,0.f,0.f}, ka = {0.f,0.f,0.f,0.f}, va = {0.f,0.f,0.f,0.f};
            qa = __builtin_amdgcn_mfma_f32_16x16x32_bf16(a0, fqw[0], qa, 0,0,0);
            qa = __builtin_amdgcn_mfma_f32_16x16x32_bf16(a1, fqw[1], qa, 0,0,0);
            ka = __builtin_amdgcn_mfma_f32_16x16x32_bf16(a0, fkw[0], ka, 0,0,0);
            ka = __builtin_amdgcn_mfma_f32_16x16x32_bf16(a1, fkw[1], ka, 0,0,0);
            va = __builtin_amdgcn_mfma_f32_16x16x32_bf16(a0, fvw[0], va, 0,0,0);
            va = __builtin_amdgcn_mfma_f32_16x16x32_bf16(a1, fvw[1], va, 0,0,0);
            #pragma unroll
            for (int j = 0; j < 4; ++j) {
                const int ro = (16*rt + lk*4 + j)*SH + col;
                qsb[ro] = f2bf(qa[j]);
                ksb[ro] = f2bf(ka[j]);
                vsb[ro] = f2bf(va[j]);
            }
        }
        // h0 (agent-0 h) + leader h2 writes overlap with QKV epilogue
        {
            const float h0 = bf2f(hs[(w*NAG)*SH + l]);
            const size_t pp = (size_t)(p0 + w);
            out[pp*128 + 64 + l] = h2l;
            float* __restrict__ outF = out + (size_t)PP*128;
            #pragma unroll
            for (int a = 1; a < NAG; ++a)
                outF[(((size_t)(a-1))*PP + pp)*128 + 64 + l] = h0;
        }
        __syncthreads();

        // ---- attention (wave w handles p_local = w): compat = masked QK^T/8
        {
            const int r0 = w * NAG;
            for (int idx = l; idx < NAG*NAG; idx += 64) {
                const int q = idx / NAG, kk = idx - q*NAG;
                float c = -1e30f;
                if (kk != q && kk != 0) {
                    float s = 0.f;
                    #pragma unroll
                    for (int c8 = 0; c8 < 8; ++c8) {
                        const short8 qv = *reinterpret_cast<const short8*>(&qsb[(r0+q )*SH + c8*8]);
                        const short8 kv = *reinterpret_cast<const short8*>(&ksb[(r0+kk)*SH + c8*8]);
                        #pragma unroll
                        for (int i = 0; i < 8; ++i)
                            s = fmaf(bf2f(qv[i]), bf2f(kv[i]), s);
                    }
                    c = s * 0.125f;
                }
                attn_s[w][q][kk] = c;
            }
        }
        __syncthreads();

        // softmax rows (lanes 0..9 per wave)
        if (l < NAG) {
            const int q = l;
            float mx = -1e30f;
            #pragma unroll
            for (int kk = 0; kk < NAG; ++kk) mx = fmaxf(mx, attn_s[w][q][kk]);
            float ex[NAG]; float sum = 0.f;
            #pragma unroll
            for (int kk = 0; kk < NAG; ++kk) { ex[kk] = __expf(attn_s[w][q][kk] - mx); sum += ex[kk]; }
            const float inv = 1.f / sum;
            #pragma unroll
            for (int kk = 0; kk < NAG; ++kk) attn_s[w][q][kk] = ex[kk] * inv;
        }
        __syncthreads();

        // m = attn @ V  (lane l = column), write bf16 into qsb (Q is dead)
        {
            const int r0 = w * NAG;
            float m[NAG];
            #pragma unroll
            for (int a = 0; a < NAG; ++a) m[a] = 0.f;
            #pragma unroll
            for (int kk = 0; kk < NAG; ++kk) {
                const float vk = bf2f(vsb[(r0+kk)*SH + l]);
                #pragma unroll
                for (int a = 0; a < NAG; ++a)
                    m[a] = fmaf(attn_s[w][a][kk], vk, m[a]);
            }
            #pragma unroll
            for (int a = 0; a < NAG; ++a) qsb[(r0+a)*SH + l] = f2bf(m[a]);
        }
        __syncthreads();

        // ---- mo = m @ Wo  → into ksb (K is dead)
        #pragma unroll
        for (int rt = 0; rt < 3; ++rt) {
            const short8 a0 = *reinterpret_cast<const short8*>(&qsb[(16*rt + lrow)*SH + lk*8]);
            const short8 a1 = *reinterpret_cast<const short8*>(&qsb[(16*rt + lrow)*SH + 32 + lk*8]);
            f32x4 mo = {0.f,0.f,0.f,0.f};
            mo = __builtin_amdgcn_mfma_f32_16x16x32_bf16(a0, fow[0], mo, 0,0,0);
            mo = __builtin_amdgcn_mfma_f32_16x16x32_bf16(a1, fow[1], mo, 0,0,0);
            #pragma unroll
            for (int j = 0; j < 4; ++j)
                ksb[(16*rt + lk*4 + j)*SH + col] = f2bf(mo[j]);
        }
        __syncthreads();

        // ---- h1 = relu([h|mo] @ W_upd + b_upd) → direct global stores
        #pragma unroll
        for (int rt = 0; rt < 3; ++rt) {
            const short8 a0 = *reinterpret_cast<const short8*>(&hs [(16*rt + lrow)*SH + lk*8]);
            const short8 a1 = *reinterpret_cast<const short8*>(&hs [(16*rt + lrow)*SH + 32 + lk*8]);
            const short8 a2 = *reinterpret_cast<const short8*>(&ksb[(16*rt + lrow)*SH + lk*8]);
            const short8 a3 = *reinterpret_cast<const short8*>(&ksb[(16*rt + lrow)*SH + 32 + lk*8]);
            f32x4 ua = {0.f,0.f,0.f,0.f};
            ua = __builtin_amdgcn_mfma_f32_16x16x32_bf16(a0, fuw[0], ua, 0,0,0);
            ua = __builtin_amdgcn_mfma_f32_16x16x32_bf16(a1, fuw[1], ua, 0,0,0);
            ua = __builtin_amdgcn_mfma_f32_16x16x32_bf16(a2, fuw[2], ua, 0,0,0);
            ua = __builtin_amdgcn_mfma_f32_16x16x32_bf16(a3, fuw[3], ua, 0,0,0);
            #pragma unroll
            for (int j = 0; j < 4; ++j) {
                const int r = 16*rt + lk*4 + j;
                if (r < RR) {
                    const int pl = r / NAG, a = r - pl*NAG;
                    const float uu = fmaxf(ua[j] + bupdv, 0.f);
                    const size_t pp = (size_t)(p0 + pl);
                    if (a == 0) out[pp*128 + col] = uu;
                    else out[(size_t)PP*128 + ((size_t)(a-1)*PP + pp)*128 + col] = uu;
                }
            }
        }
    }
}

extern "C" void kernel_launch(void* const* d_in, const int* in_sizes, int n_in,
                              void* d_out, int out_size, void* d_ws, size_t ws_size,
                              hipStream_t stream) {
    const float* inp    = (const float*)d_in[0];
    const float* W_enc  = (const float*)d_in[1];
    const float* b_enc  = (const float*)d_in[2];
    const float* W_goal = (const float*)d_in[3];
    const float* b_goal = (const float*)d_in[4];
    const float* Wq     = (const float*)d_in[5];
    const float* Wk     = (const float*)d_in[6];
    const float* Wv     = (const float*)d_in[7];
    const float* Wo     = (const float*)d_in[8];
    const float* W_upd  = (const float*)d_in[9];
    const float* b_upd  = (const float*)d_in[10];

    hipLaunchKernelGGL(mpnn_mfma, dim3(NBLK), dim3(256), 0, stream,
                       inp, W_enc, b_enc, W_goal, b_goal,
                       Wq, Wk, Wv, Wo, W_upd, b_upd, (float*)d_out);
}

// Round 3
// 274.145 us; speedup vs baseline: 2.9138x; 1.7476x over previous
//
#include <hip/hip_runtime.h>
#include <math.h>

#define NAG 10
#define PP  65536
#define EE  64
#define INW 16
#define TP  4              // p's per group (one wave each)
#define RR  (TP*NAG)       // 40 rows
#define SH  72             // bf16 LDS stride for 64-wide tiles
#define SX  40             // bf16 LDS stride for X tile
#define SOT 132            // f32 LDS stride for output tile
#define NBLK 1024
#define NGRP (PP/TP)       // 16384

typedef __attribute__((ext_vector_type(8))) short short8;
typedef __attribute__((ext_vector_type(4))) float f32x4;

__device__ __forceinline__ short f2bf(float x){
    unsigned u = __float_as_uint(x);
    u += 0x7FFF + ((u >> 16) & 1);          // RNE
    return (short)(u >> 16);
}
__device__ __forceinline__ float bf2f(short s){
    return __uint_as_float(((unsigned)(unsigned short)s) << 16);
}

__global__ __launch_bounds__(256, 4) void mpnn_mfma2(
    const float* __restrict__ inp,
    const float* __restrict__ W_enc, const float* __restrict__ b_enc,
    const float* __restrict__ W_goal, const float* __restrict__ b_goal,
    const float* __restrict__ Wq, const float* __restrict__ Wk,
    const float* __restrict__ Wv, const float* __restrict__ Wo,
    const float* __restrict__ W_upd, const float* __restrict__ b_upd,
    float* __restrict__ out)
{
    // byte pool aliased three ways over the kernel's life:
    //  init:   Wc (64x64 f32, 16384 B)
    //  main:   hs | qsb | ksb | vsb  (4 x 48*SH bf16 = 27648 B)
    //  epilog: outt (40 x SOT f32 = 21120 B)
    __shared__ __align__(16) char pool[4 * 48 * SH * 2];
    __shared__ __align__(16) short Xs[48 * SX];
    __shared__ float attn_s[TP][NAG][12];
    __shared__ float goal_s[TP][2];

    short* const hs   = (short*)pool;
    short* const qsb  = hs  + 48*SH;
    short* const ksb  = qsb + 48*SH;
    short* const vsb  = ksb + 48*SH;
    float* const outt = (float*)pool;
    float* const Wc   = (float*)pool;

    const int tid  = threadIdx.x;
    const int w    = tid >> 6;      // wave id == col-tile == p_local for attention
    const int l    = tid & 63;
    const int lrow = l & 15;
    const int lk   = l >> 4;
    const int col  = 16*w + lrow;

    // ---- Wc = Wo @ W_upd[64:128]  (once per block, fp32 in LDS)
    for (int i = tid; i < EE*EE; i += 256) {
        const int k = i >> 6, n = i & 63;
        float s = 0.f;
        #pragma unroll 8
        for (int d = 0; d < EE; ++d)
            s = fmaf(Wo[k*EE + d], W_upd[(EE + d)*EE + n], s);
        Wc[i] = s;
    }
    __syncthreads();

    // ---- B-fragment preload (all weights live in registers)
    short8 fenc, fqw[2], fkw[2], fvw[2], fuw[2], fcw[2];
    #pragma unroll
    for (int j = 0; j < 8; ++j) {
        int k = lk*8 + j;
        fenc[j] = (k < 14) ? f2bf(W_enc[k*EE + col]) : (short)0;
    }
    #pragma unroll
    for (int ks = 0; ks < 2; ++ks) {
        #pragma unroll
        for (int j = 0; j < 8; ++j) {
            int k = 32*ks + lk*8 + j;
            fqw[ks][j] = f2bf(Wq[k*EE + col]);
            fkw[ks][j] = f2bf(Wk[k*EE + col]);
            fvw[ks][j] = f2bf(Wv[k*EE + col]);
            fuw[ks][j] = f2bf(W_upd[k*EE + col]);
            fcw[ks][j] = f2bf(Wc[k*EE + col]);
        }
    }
    const float bencv = b_enc[col];
    const float bupdv = b_upd[col];
    const float wg0 = W_goal[l], wg1 = W_goal[EE + l], bg = b_goal[l];

    // zero X once: per-group writes only touch cols<16 of rows<40; rest stays 0
    for (int i = tid; i < 48*SX; i += 256) Xs[i] = 0;

    // ---- input prefetch setup: lane -> one float4 (row r = pl*NAG+a, quarter q)
    const bool hasx = tid < RR*4;
    const int  r_ = tid >> 2, q_ = tid & 3;
    const int  pl_ = r_ / NAG, a_ = r_ - pl_*NAG;
    const size_t xbase = (size_t)a_*PP*INW + (size_t)pl_*INW + (size_t)q_*4;
    float4 xin = {0,0,0,0};
    if (hasx) xin = *(const float4*)(inp + xbase + (size_t)blockIdx.x * (TP*INW));

    for (int g = blockIdx.x; g < NGRP; g += NBLK) {
        const int p0 = g * TP;
        __syncthreads();   // A: prior store-phase reads of pool + enc reads of Xs done

        // ---- stage X (bf16) + goal from prefetched regs
        if (hasx) {
            short* xr = &Xs[r_*SX + q_*4];
            xr[0] = f2bf(xin.x); xr[1] = f2bf(xin.y);
            if (q_ == 3 && a_ == 0) {
                goal_s[pl_][0] = xin.z; goal_s[pl_][1] = xin.w;
            } else {
                xr[2] = f2bf(xin.z); xr[3] = f2bf(xin.w);
            }
        }
        __syncthreads();   // B

        // prefetch next group's input (latency hidden under compute)
        if (hasx && g + NBLK < NGRP)
            xin = *(const float4*)(inp + xbase + (size_t)(g + NBLK) * (TP*INW));

        const float h2l = fmaxf(fmaf(goal_s[w][0], wg0,
                           fmaf(goal_s[w][1], wg1, bg)), 0.f);

        // ---- encoder: h = relu(X @ W_enc + b_enc)
        #pragma unroll
        for (int rt = 0; rt < 3; ++rt) {
            const short8 a0 = *reinterpret_cast<const short8*>(&Xs[(16*rt + lrow)*SX + lk*8]);
            f32x4 acc = {0.f,0.f,0.f,0.f};
            acc = __builtin_amdgcn_mfma_f32_16x16x32_bf16(a0, fenc, acc, 0,0,0);
            #pragma unroll
            for (int j = 0; j < 4; ++j)
                hs[(16*rt + lk*4 + j)*SH + col] = f2bf(fmaxf(acc[j] + bencv, 0.f));
        }
        __syncthreads();   // C

        // ---- Q,K,V = h @ Wq/Wk/Wv
        #pragma unroll
        for (int rt = 0; rt < 3; ++rt) {
            const short8 a0 = *reinterpret_cast<const short8*>(&hs[(16*rt + lrow)*SH + lk*8]);
            const short8 a1 = *reinterpret_cast<const short8*>(&hs[(16*rt + lrow)*SH + 32 + lk*8]);
            f32x4 qa = {0.f,0.f,0.f,0.f}, ka = {0.f,0.f,0.f,0.f}, va = {0.f,0.f,0.f,0.f};
            qa = __builtin_amdgcn_mfma_f32_16x16x32_bf16(a0, fqw[0], qa, 0,0,0);
            qa = __builtin_amdgcn_mfma_f32_16x16x32_bf16(a1, fqw[1], qa, 0,0,0);
            ka = __builtin_amdgcn_mfma_f32_16x16x32_bf16(a0, fkw[0], ka, 0,0,0);
            ka = __builtin_amdgcn_mfma_f32_16x16x32_bf16(a1, fkw[1], ka, 0,0,0);
            va = __builtin_amdgcn_mfma_f32_16x16x32_bf16(a0, fvw[0], va, 0,0,0);
            va = __builtin_amdgcn_mfma_f32_16x16x32_bf16(a1, fvw[1], va, 0,0,0);
            #pragma unroll
            for (int j = 0; j < 4; ++j) {
                const int ro = (16*rt + lk*4 + j)*SH + col;
                qsb[ro] = f2bf(qa[j]);
                ksb[ro] = f2bf(ka[j]);
                vsb[ro] = f2bf(va[j]);
            }
        }
        const float h0 = bf2f(hs[(w*NAG)*SH + l]);   // agent-0 h, element l, p = p0+w
        __syncthreads();   // D

        // ---- attention (all phases within wave w for p_local = w; DS is in-order per wave)
        {
            const int r0 = w * NAG;
            // compat = masked QK^T / 8
            for (int idx = l; idx < NAG*NAG; idx += 64) {
                const int q = idx / NAG, kk = idx - q*NAG;
                float c = -1e30f;
                if (kk != q && kk != 0) {
                    float s = 0.f;
                    #pragma unroll
                    for (int c8 = 0; c8 < 8; ++c8) {
                        const short8 qv = *reinterpret_cast<const short8*>(&qsb[(r0+q )*SH + c8*8]);
                        const short8 kv = *reinterpret_cast<const short8*>(&ksb[(r0+kk)*SH + c8*8]);
                        #pragma unroll
                        for (int i = 0; i < 8; ++i)
                            s = fmaf(bf2f(qv[i]), bf2f(kv[i]), s);
                    }
                    c = s * 0.125f;
                }
                attn_s[w][q][kk] = c;
            }
            // softmax rows (lanes 0..9)
            if (l < NAG) {
                const int q = l;
                float mx = -1e30f;
                #pragma unroll
                for (int kk = 0; kk < NAG; ++kk) mx = fmaxf(mx, attn_s[w][q][kk]);
                float ex[NAG]; float sum = 0.f;
                #pragma unroll
                for (int kk = 0; kk < NAG; ++kk) { ex[kk] = __expf(attn_s[w][q][kk] - mx); sum += ex[kk]; }
                const float inv = 1.f / sum;
                #pragma unroll
                for (int kk = 0; kk < NAG; ++kk) attn_s[w][q][kk] = ex[kk] * inv;
            }
            // m = attn @ V  -> bf16 into qsb (Q dead; same-wave rows only)
            float m[NAG];
            #pragma unroll
            for (int a = 0; a < NAG; ++a) m[a] = 0.f;
            #pragma unroll
            for (int kk = 0; kk < NAG; ++kk) {
                const float vk = bf2f(vsb[(r0+kk)*SH + l]);
                #pragma unroll
                for (int a = 0; a < NAG; ++a)
                    m[a] = fmaf(attn_s[w][a][kk], vk, m[a]);
            }
            #pragma unroll
            for (int a = 0; a < NAG; ++a) qsb[(r0+a)*SH + l] = f2bf(m[a]);
        }
        __syncthreads();   // G

        // ---- u = relu(h @ Wu_top + m @ Wc + b_upd)  (Wo folded into Wc)
        f32x4 uacc[3];
        #pragma unroll
        for (int rt = 0; rt < 3; ++rt) {
            const short8 a0 = *reinterpret_cast<const short8*>(&hs [(16*rt + lrow)*SH + lk*8]);
            const short8 a1 = *reinterpret_cast<const short8*>(&hs [(16*rt + lrow)*SH + 32 + lk*8]);
            const short8 a2 = *reinterpret_cast<const short8*>(&qsb[(16*rt + lrow)*SH + lk*8]);
            const short8 a3 = *reinterpret_cast<const short8*>(&qsb[(16*rt + lrow)*SH + 32 + lk*8]);
            f32x4 ua = {0.f,0.f,0.f,0.f};
            ua = __builtin_amdgcn_mfma_f32_16x16x32_bf16(a0, fuw[0], ua, 0,0,0);
            ua = __builtin_amdgcn_mfma_f32_16x16x32_bf16(a1, fuw[1], ua, 0,0,0);
            ua = __builtin_amdgcn_mfma_f32_16x16x32_bf16(a2, fcw[0], ua, 0,0,0);
            ua = __builtin_amdgcn_mfma_f32_16x16x32_bf16(a3, fcw[1], ua, 0,0,0);
            uacc[rt] = ua;
        }
        __syncthreads();   // H: all pool reads done -> safe to overlay outt

        // ---- build fp32 output tile in LDS
        #pragma unroll
        for (int rt = 0; rt < 3; ++rt) {
            #pragma unroll
            for (int j = 0; j < 4; ++j) {
                const int r = 16*rt + lk*4 + j;
                if (r < RR) outt[r*SOT + col] = fmaxf(uacc[rt][j] + bupdv, 0.f);
            }
        }
        outt[(w*NAG)*SOT + 64 + l] = h2l;
        #pragma unroll
        for (int a = 1; a < NAG; ++a)
            outt[(w*NAG + a)*SOT + 64 + l] = h0;
        __syncthreads();   // I

        // ---- coalesced full-line stores: 10 chunks of 2048 B contiguous
        float* __restrict__ outF = out + (size_t)PP*128;
        #pragma unroll
        for (int it = 0; it < 5; ++it) {
            const int flat   = it*256 + tid;
            const int a      = flat >> 7;
            const int within = flat & 127;
            const int pl     = within >> 5;
            const int j4     = within & 31;
            const float4 v = *(const float4*)&outt[(pl*NAG + a)*SOT + j4*4];
            float* dst = (a == 0)
                ? (out  + ((size_t)(p0 + pl))*128 + j4*4)
                : (outF + ((size_t)(a-1)*PP + (size_t)(p0 + pl))*128 + j4*4);
            *(float4*)dst = v;
        }
    }
}

extern "C" void kernel_launch(void* const* d_in, const int* in_sizes, int n_in,
                              void* d_out, int out_size, void* d_ws, size_t ws_size,
                              hipStream_t stream) {
    const float* inp    = (const float*)d_in[0];
    const float* W_enc  = (const float*)d_in[1];
    const float* b_enc  = (const float*)d_in[2];
    const float* W_goal = (const float*)d_in[3];
    const float* b_goal = (const float*)d_in[4];
    const float* Wq     = (const float*)d_in[5];
    const float* Wk     = (const float*)d_in[6];
    const float* Wv     = (const float*)d_in[7];
    const float* Wo     = (const float*)d_in[8];
    const float* W_upd  = (const float*)d_in[9];
    const float* b_upd  = (const float*)d_in[10];

    hipLaunchKernelGGL(mpnn_mfma2, dim3(NBLK), dim3(256), 0, stream,
                       inp, W_enc, b_enc, W_goal, b_goal,
                       Wq, Wk, Wv, Wo, W_upd, b_upd, (float*)d_out);
}

// Round 4
// 255.035 us; speedup vs baseline: 3.1322x; 1.0749x over previous
//
#include <hip/hip_runtime.h>
#include <math.h>

#define NAG 10
#define PP  65536
#define EE  64
#define INW 16
#define TP  4              // p's per group (one wave each)
#define RR  (TP*NAG)       // 40 rows
#define SH  72             // bf16 LDS stride for 64-wide tiles
#define SX  40             // bf16 LDS stride for X tile
#define SOT 132            // f32 LDS stride for output tile
#define NBLK 1024
#define NGRP (PP/TP)       // 16384

typedef __attribute__((ext_vector_type(8))) short short8;
typedef __attribute__((ext_vector_type(4))) float f32x4;

__device__ __forceinline__ short f2bf(float x){
    unsigned u = __float_as_uint(x);
    return (short)((u + 0x8000u) >> 16);     // round-nearest, ties away (2 VALU ops)
}
__device__ __forceinline__ float bf2f(short s){
    return __uint_as_float(((unsigned)(unsigned short)s) << 16);
}

__global__ __launch_bounds__(256, 4) void mpnn_mfma3(
    const float* __restrict__ inp,
    const float* __restrict__ W_enc, const float* __restrict__ b_enc,
    const float* __restrict__ W_goal, const float* __restrict__ b_goal,
    const float* __restrict__ Wq, const float* __restrict__ Wk,
    const float* __restrict__ Wv, const float* __restrict__ Wo,
    const float* __restrict__ W_upd, const float* __restrict__ b_upd,
    float* __restrict__ out)
{
    // byte pool aliased: init Wc (16 KB) | main hs|qsb|ksb|vsb (27.6 KB) | epilog outt (21.1 KB)
    __shared__ __align__(16) char pool[4 * 48 * SH * 2];
    __shared__ __align__(16) short Xs[48 * SX];
    __shared__ __align__(16) float attn_s[TP][NAG][12];
    __shared__ float goal_s[TP][2];

    short* const hs   = (short*)pool;
    short* const qsb  = hs  + 48*SH;
    short* const ksb  = qsb + 48*SH;
    short* const vsb  = ksb + 48*SH;
    float* const outt = (float*)pool;
    float* const Wc   = (float*)pool;

    const int tid  = threadIdx.x;
    const int w    = tid >> 6;      // wave id == col-tile == p_local for attention
    const int l    = tid & 63;
    const int lrow = l & 15;
    const int lk   = l >> 4;
    const int col  = 16*w + lrow;

    // ---- Wc = Wo @ W_upd[64:128]  (once per block, fp32 in LDS)
    for (int i = tid; i < EE*EE; i += 256) {
        const int k = i >> 6, n = i & 63;
        float s = 0.f;
        #pragma unroll 8
        for (int d = 0; d < EE; ++d)
            s = fmaf(Wo[k*EE + d], W_upd[(EE + d)*EE + n], s);
        Wc[i] = s;
    }
    __syncthreads();

    // ---- B-fragment preload (all weights live in registers)
    short8 fenc, fqw[2], fkw[2], fvw[2], fuw[2], fcw[2];
    #pragma unroll
    for (int j = 0; j < 8; ++j) {
        int k = lk*8 + j;
        fenc[j] = (k < 14) ? f2bf(W_enc[k*EE + col]) : (short)0;
    }
    #pragma unroll
    for (int ks = 0; ks < 2; ++ks) {
        #pragma unroll
        for (int j = 0; j < 8; ++j) {
            int k = 32*ks + lk*8 + j;
            fqw[ks][j] = f2bf(Wq[k*EE + col]);
            fkw[ks][j] = f2bf(Wk[k*EE + col]);
            fvw[ks][j] = f2bf(Wv[k*EE + col]);
            fuw[ks][j] = f2bf(W_upd[k*EE + col]);
            fcw[ks][j] = f2bf(Wc[k*EE + col]);
        }
    }
    const float bencv = b_enc[col];
    const float bupdv = b_upd[col];
    const float wg0 = W_goal[l], wg1 = W_goal[EE + l], bg = b_goal[l];

    // zero X once: per-group writes only touch cols<16 of rows<40; rest stays 0
    for (int i = tid; i < 48*SX; i += 256) Xs[i] = 0;

    // ---- input prefetch: lane -> one float4 (row r = pl*NAG+a, quarter q)
    const bool hasx = tid < RR*4;
    const int  r_ = tid >> 2, q_ = tid & 3;
    const int  pl_ = r_ / NAG, a_ = r_ - pl_*NAG;
    const size_t xbase = (size_t)a_*PP*INW + (size_t)pl_*INW + (size_t)q_*4;
    f32x4 xin = {0.f,0.f,0.f,0.f};
    if (hasx) xin = __builtin_nontemporal_load(
        (const f32x4*)(inp + xbase + (size_t)blockIdx.x * (TP*INW)));

    for (int g = blockIdx.x; g < NGRP; g += NBLK) {
        const int p0 = g * TP;
        __syncthreads();   // A: prior store-phase reads of pool done

        // ---- stage X (bf16) + goal from prefetched regs
        if (hasx) {
            short* xr = &Xs[r_*SX + q_*4];
            xr[0] = f2bf(xin[0]); xr[1] = f2bf(xin[1]);
            if (q_ == 3 && a_ == 0) {
                goal_s[pl_][0] = xin[2]; goal_s[pl_][1] = xin[3];
            } else {
                xr[2] = f2bf(xin[2]); xr[3] = f2bf(xin[3]);
            }
        }
        __syncthreads();   // B

        // prefetch next group's input (latency hidden under compute)
        if (hasx && g + NBLK < NGRP)
            xin = __builtin_nontemporal_load(
                (const f32x4*)(inp + xbase + (size_t)(g + NBLK) * (TP*INW)));

        const float h2l = fmaxf(fmaf(goal_s[w][0], wg0,
                           fmaf(goal_s[w][1], wg1, bg)), 0.f);

        // ---- encoder: h = relu(X @ W_enc + b_enc)
        #pragma unroll
        for (int rt = 0; rt < 3; ++rt) {
            const short8 a0 = *reinterpret_cast<const short8*>(&Xs[(16*rt + lrow)*SX + lk*8]);
            f32x4 acc = {0.f,0.f,0.f,0.f};
            acc = __builtin_amdgcn_mfma_f32_16x16x32_bf16(a0, fenc, acc, 0,0,0);
            #pragma unroll
            for (int j = 0; j < 4; ++j)
                hs[(16*rt + lk*4 + j)*SH + col] = f2bf(fmaxf(acc[j] + bencv, 0.f));
        }
        __syncthreads();   // C

        // ---- Q,K,V = h @ Wq/Wk/Wv ; cache the h A-frags for the upd phase
        short8 hA0[3], hA1[3];
        #pragma unroll
        for (int rt = 0; rt < 3; ++rt) {
            hA0[rt] = *reinterpret_cast<const short8*>(&hs[(16*rt + lrow)*SH + lk*8]);
            hA1[rt] = *reinterpret_cast<const short8*>(&hs[(16*rt + lrow)*SH + 32 + lk*8]);
            f32x4 qa = {0.f,0.f,0.f,0.f}, ka = {0.f,0.f,0.f,0.f}, va = {0.f,0.f,0.f,0.f};
            qa = __builtin_amdgcn_mfma_f32_16x16x32_bf16(hA0[rt], fqw[0], qa, 0,0,0);
            qa = __builtin_amdgcn_mfma_f32_16x16x32_bf16(hA1[rt], fqw[1], qa, 0,0,0);
            ka = __builtin_amdgcn_mfma_f32_16x16x32_bf16(hA0[rt], fkw[0], ka, 0,0,0);
            ka = __builtin_amdgcn_mfma_f32_16x16x32_bf16(hA1[rt], fkw[1], ka, 0,0,0);
            va = __builtin_amdgcn_mfma_f32_16x16x32_bf16(hA0[rt], fvw[0], va, 0,0,0);
            va = __builtin_amdgcn_mfma_f32_16x16x32_bf16(hA1[rt], fvw[1], va, 0,0,0);
            #pragma unroll
            for (int j = 0; j < 4; ++j) {
                const int ro = (16*rt + lk*4 + j)*SH + col;
                qsb[ro] = f2bf(qa[j]);
                ksb[ro] = f2bf(ka[j]);
                vsb[ro] = f2bf(va[j]);
            }
        }
        const float h0 = bf2f(hs[(w*NAG)*SH + l]);   // agent-0 h, elem l, p=p0+w
        __syncthreads();   // D

        // ---- attention for p = w (wave-local; DS ops in-order per wave)
        {
            const int r0 = w * NAG;
            // S^T = K @ Q^T via MFMA: B-frag of Q^T == A-frag addressing of Q
            const short8 aK0 = *reinterpret_cast<const short8*>(&ksb[(r0+lrow)*SH + lk*8]);
            const short8 aK1 = *reinterpret_cast<const short8*>(&ksb[(r0+lrow)*SH + 32 + lk*8]);
            const short8 aQ0 = *reinterpret_cast<const short8*>(&qsb[(r0+lrow)*SH + lk*8]);
            const short8 aQ1 = *reinterpret_cast<const short8*>(&qsb[(r0+lrow)*SH + 32 + lk*8]);
            f32x4 st = {0.f,0.f,0.f,0.f};
            st = __builtin_amdgcn_mfma_f32_16x16x32_bf16(aK0, aQ0, st, 0,0,0);
            st = __builtin_amdgcn_mfma_f32_16x16x32_bf16(aK1, aQ1, st, 0,0,0);
            // lane holds S[q=lrow][k=lk*4+j] in st[j]
            const int q = lrow;
            float c[4]; float mx4 = -1e30f;
            #pragma unroll
            for (int j = 0; j < 4; ++j) {
                const int k = lk*4 + j;
                const bool valid = (q < NAG) && (k < NAG) && (k != q) && (k != 0);
                c[j] = valid ? st[j] * 0.125f : -1e30f;
                mx4 = fmaxf(mx4, c[j]);
            }
            float mx = fmaxf(mx4, __shfl_xor(mx4, 16, 64));
            mx = fmaxf(mx, __shfl_xor(mx, 32, 64));
            float e[4], s4 = 0.f;
            #pragma unroll
            for (int j = 0; j < 4; ++j) { e[j] = __expf(c[j] - mx); s4 += e[j]; }
            float s = s4;
            s += __shfl_xor(s, 16, 64);
            s += __shfl_xor(s, 32, 64);
            const float inv = 1.f / s;
            if (q < NAG) {
                #pragma unroll
                for (int j = 0; j < 4; ++j) {
                    const int k = lk*4 + j;
                    if (k < NAG) attn_s[w][q][k] = e[j] * inv;
                }
            }

            // m = attn @ V (lane = column), write bf16 into qsb (Q dead)
            float vv[NAG];
            #pragma unroll
            for (int kk = 0; kk < NAG; ++kk) vv[kk] = bf2f(vsb[(r0+kk)*SH + l]);
            #pragma unroll
            for (int a = 0; a < NAG; ++a) {
                float m = 0.f;
                #pragma unroll
                for (int t = 0; t < 5; ++t) {
                    const float2 pv = *reinterpret_cast<const float2*>(&attn_s[w][a][2*t]);
                    m = fmaf(pv.x, vv[2*t], fmaf(pv.y, vv[2*t+1], m));
                }
                qsb[(r0+a)*SH + l] = f2bf(m);
            }
        }
        __syncthreads();   // G

        // ---- u = relu(h @ Wu_top + m @ Wc + b_upd)   (Wo folded into Wc)
        f32x4 uacc[3];
        #pragma unroll
        for (int rt = 0; rt < 3; ++rt) {
            const short8 a2 = *reinterpret_cast<const short8*>(&qsb[(16*rt + lrow)*SH + lk*8]);
            const short8 a3 = *reinterpret_cast<const short8*>(&qsb[(16*rt + lrow)*SH + 32 + lk*8]);
            f32x4 ua = {0.f,0.f,0.f,0.f};
            ua = __builtin_amdgcn_mfma_f32_16x16x32_bf16(hA0[rt], fuw[0], ua, 0,0,0);
            ua = __builtin_amdgcn_mfma_f32_16x16x32_bf16(hA1[rt], fuw[1], ua, 0,0,0);
            ua = __builtin_amdgcn_mfma_f32_16x16x32_bf16(a2,      fcw[0], ua, 0,0,0);
            ua = __builtin_amdgcn_mfma_f32_16x16x32_bf16(a3,      fcw[1], ua, 0,0,0);
            uacc[rt] = ua;
        }
        __syncthreads();   // H: all pool reads done -> overlay outt

        // ---- build fp32 output tile in LDS
        #pragma unroll
        for (int rt = 0; rt < 3; ++rt) {
            #pragma unroll
            for (int j = 0; j < 4; ++j) {
                const int r = 16*rt + lk*4 + j;
                if (r < RR) outt[r*SOT + col] = fmaxf(uacc[rt][j] + bupdv, 0.f);
            }
        }
        outt[(w*NAG)*SOT + 64 + l] = h2l;
        #pragma unroll
        for (int a = 1; a < NAG; ++a)
            outt[(w*NAG + a)*SOT + 64 + l] = h0;
        __syncthreads();   // I

        // ---- coalesced full-line nontemporal stores: 1024 B / wave-instr
        float* __restrict__ outF = out + (size_t)PP*128;
        #pragma unroll
        for (int it = 0; it < 5; ++it) {
            const int flat   = it*256 + tid;
            const int a      = flat >> 7;
            const int within = flat & 127;
            const int pl     = within >> 5;
            const int j4     = within & 31;
            const f32x4 v = *reinterpret_cast<const f32x4*>(&outt[(pl*NAG + a)*SOT + j4*4]);
            float* dst = (a == 0)
                ? (out  + ((size_t)(p0 + pl))*128 + j4*4)
                : (outF + ((size_t)(a-1)*PP + (size_t)(p0 + pl))*128 + j4*4);
            __builtin_nontemporal_store(v, (f32x4*)dst);
        }
    }
}

extern "C" void kernel_launch(void* const* d_in, const int* in_sizes, int n_in,
                              void* d_out, int out_size, void* d_ws, size_t ws_size,
                              hipStream_t stream) {
    const float* inp    = (const float*)d_in[0];
    const float* W_enc  = (const float*)d_in[1];
    const float* b_enc  = (const float*)d_in[2];
    const float* W_goal = (const float*)d_in[3];
    const float* b_goal = (const float*)d_in[4];
    const float* Wq     = (const float*)d_in[5];
    const float* Wk     = (const float*)d_in[6];
    const float* Wv     = (const float*)d_in[7];
    const float* Wo     = (const float*)d_in[8];
    const float* W_upd  = (const float*)d_in[9];
    const float* b_upd  = (const float*)d_in[10];

    hipLaunchKernelGGL(mpnn_mfma3, dim3(NBLK), dim3(256), 0, stream,
                       inp, W_enc, b_enc, W_goal, b_goal,
                       Wq, Wk, Wv, Wo, W_upd, b_upd, (float*)d_out);
}